// Round 10
// baseline (134.010 us; speedup 1.0000x reference)
//
#include <hip/hip_runtime.h>
#include <stdint.h>

// N=4096, D=1024 -> M = [Q|K] : 4096 x 2048, Mt = M^T (fp8 e4m3, K-permuted)
// loss = [ sum_{a,b} s_a s_b (M^T M)_ab^2 ] / (N*(N-1)), s_a=+1 (a<1024), -1 else
// R10: grouped gram tiles 128x256 (1 A-panel x 1 B-superpanel): 72 tiles x
// KSPLIT=8 = 576 blocks, 48 KiB LDS, 128 MFMA/wave/barrier (2x R6) and half
// the barrier-pairs. Straddling tiles alias A into B's LDS panel; reduce
// decodes MFMA layout to apply weight {0,1,2} and block sign.
#define N_ROWS 4096
#define DIMS   1024
#define TGR    16      // row blocks of 128
#define NJOBT  72      // sum_{R=0}^{15} (8 - (R>>1))
#define KSPLIT 8
#define KCHUNK 512     // 4096/KSPLIT (fp8 bytes)
#define BKB    128     // staged bytes per row per iteration
#define NITER  4       // KCHUNK/BKB

typedef __attribute__((ext_vector_type(2))) long longx2;
typedef __attribute__((ext_vector_type(8))) unsigned short ushort8;
typedef __attribute__((ext_vector_type(4))) float f32x4;

__device__ __forceinline__ unsigned short f2bf(float f) {
  union { float f; unsigned int u; } c; c.f = f;
  unsigned int u = c.u;
  return (unsigned short)((u + 0x7fffu + ((u >> 16) & 1u)) >> 16);
}
__device__ __forceinline__ float bf2f(unsigned short v) {
  union { float f; unsigned int u; } c; c.u = ((unsigned int)v) << 16;
  return c.f;
}
__device__ __forceinline__ unsigned int pk4_fp8(float a, float b, float c, float d) {
  int v = __builtin_amdgcn_cvt_pk_fp8_f32(a, b, 0, false);
  v = __builtin_amdgcn_cvt_pk_fp8_f32(c, d, v, true);
  return (unsigned int)v;
}
__device__ __forceinline__ void async_cp16(const unsigned char* g, void* lds) {
  __builtin_amdgcn_global_load_lds(
      (const __attribute__((address_space(1))) void*)g,
      (__attribute__((address_space(3))) void*)lds, 16, 0, 0);
}

// ---------------------------------------------------------------------------
// K1: inverse row norms (R6-verified); zero d_out.
// ---------------------------------------------------------------------------
__global__ __launch_bounds__(256) void rownorm_kernel(
    const float* __restrict__ fq, const float* __restrict__ fk,
    float* __restrict__ invq, float* __restrict__ invk, float* __restrict__ out) {
  if (blockIdx.x == 0 && blockIdx.y == 0 && threadIdx.x == 0) out[0] = 0.0f;
  const int w = threadIdx.x >> 6, lane = threadIdx.x & 63;
  const int row = blockIdx.x * 4 + w;
  const float* src = blockIdx.y ? fk : fq;
  float* dst = blockIdx.y ? invk : invq;
  const float4* s4 = (const float4*)(src + (size_t)row * DIMS);
  float ss = 0.0f;
  #pragma unroll
  for (int s = 0; s < 4; ++s) {
    float4 v = s4[lane + 64 * s];
    ss += v.x * v.x + v.y * v.y + v.z * v.z + v.w * v.w;
  }
  #pragma unroll
  for (int off = 32; off > 0; off >>= 1) ss += __shfl_xor(ss, off);
  if (lane == 0) dst[row] = 1.0f / sqrtf(ss);  // eps terms cancel (~3e-9 rel)
}

// ---------------------------------------------------------------------------
// K2: Mt[a][perm(i)] = fp8(normalized), transposed via LDS (R6-verified;
// reads are 64-lane contiguous, writes cover full 128B permuted runs).
// ---------------------------------------------------------------------------
__global__ __launch_bounds__(256) void transpose_scale_kernel(
    const float* __restrict__ fq, const float* __restrict__ fk,
    const float* __restrict__ invq, const float* __restrict__ invk,
    unsigned char* __restrict__ Mt) {
  __shared__ unsigned short tile[64][260];
  const int i0 = blockIdx.x * 256;
  const int a0 = blockIdx.y * 64;
  const int w = threadIdx.x >> 6, lane = threadIdx.x & 63;
  const float* src;
  const float* inv;
  int acol;
  if (a0 < DIMS) { src = fq; inv = invq; acol = a0 + lane; }
  else           { src = fk; inv = invk; acol = a0 - DIMS + lane; }

  for (int c0 = 0; c0 < 64; c0 += 4) {
    ushort4 v;
    unsigned short* vp = (unsigned short*)&v;
    #pragma unroll
    for (int c = 0; c < 4; ++c) {
      const int i = i0 + w * 64 + c0 + c;
      vp[c] = f2bf(src[(size_t)i * DIMS + acol] * inv[i]);
    }
    *(ushort4*)&tile[lane][w * 64 + c0] = v;
  }
  __syncthreads();
  const int il = (lane * 4) & 127;
  const int blk = (i0 + lane * 4) >> 7;
  const int q = (il >> 3) & 3, s0b = (il >> 5) & 1, s1b = (il >> 6) & 1;
  const int pos = q * 32 + s1b * 16 + s0b * 8 + (il & 7);
  #pragma unroll
  for (int r = 0; r < 16; ++r) {
    const int al = w * 16 + r;
    ushort4 v = *(const ushort4*)&tile[al][lane * 4];
    const unsigned int p8 = pk4_fp8(bf2f(v.x), bf2f(v.y), bf2f(v.z), bf2f(v.w));
    *(unsigned int*)(Mt + (size_t)(a0 + al) * N_ROWS + blk * 128 + pos) = p8;
  }
}

// ---------------------------------------------------------------------------
// K3: grouped partial Gram: output tile 128 (rows, block R) x 256 (cols,
// superblock C), jobs (R,C) with C >= R>>1 (72 tiles) x KSPLIT. Wave tile
// 64x128: acc[4][8]. LDS: A rows 0..127 (16 KiB) + B rows 0..255 (32 KiB).
// Straddling tiles (R>>1 == C) read A from inside the B panel.
// ---------------------------------------------------------------------------
__global__ __launch_bounds__(256, 2) void gram_grouped_kernel(
    const unsigned char* __restrict__ Mt, unsigned short* __restrict__ Gp) {
  __shared__ __align__(16) char smem[384 * 128];  // 48 KiB

  const int job = blockIdx.x;
  const int t = job >> 3;
  const int kc = job & 7;
  int R = 0, rem = t;
  while (rem >= 8 - (R >> 1)) { rem -= 8 - (R >> 1); ++R; }
  const int C = (R >> 1) + rem;
  const bool strad = ((R >> 1) == C);   // A-panel aliases into B-panel

  const int tid = threadIdx.x, w = tid >> 6, lane = tid & 63;
  const int rl = lane >> 3;
  const int cl = (lane & 7) ^ rl;       // chunk swizzle (verified R1..R9)

  const int ml = lane & 15, quad = lane >> 4;
  const int ar0 = (w >> 1) * 64, bc0 = (w & 1) * 128;
  const char* aBase = strad ? (smem + 16384 + (R & 1) * 16384) : smem;
  const char* bBase = smem + 16384;

  f32x4 acc[4][8] = {};

  for (int it = 0; it < NITER; ++it) {
    const size_t kof = (size_t)kc * KCHUNK + (size_t)it * BKB + cl * 16;
    if (!strad) {
      #pragma unroll
      for (int g = 0; g < 12; ++g) {
        const int rho = w * 96 + g * 8;     // LDS row base (uniform per wave)
        const int grow = (rho < 128) ? (R * 128 + rho) : (C * 256 + rho - 128);
        async_cp16(Mt + (size_t)(grow + rl) * N_ROWS + kof,
                   smem + rho * 128 + lane * 16);
      }
    } else {
      #pragma unroll
      for (int g = 0; g < 8; ++g) {
        const int rho = 128 + w * 64 + g * 8;
        const int grow = C * 256 + rho - 128;
        async_cp16(Mt + (size_t)(grow + rl) * N_ROWS + kof,
                   smem + rho * 128 + lane * 16);
      }
    }
    __syncthreads();

    longx2 a[4][2], b[8][2];
    #pragma unroll
    for (int s1 = 0; s1 < 2; ++s1) {
      const int slot = ((quad * 2 + s1) ^ (ml & 7)) * 16;
      #pragma unroll
      for (int i = 0; i < 4; ++i)
        a[i][s1] = *(const longx2*)(aBase + (ar0 + i * 16 + ml) * 128 + slot);
      #pragma unroll
      for (int j = 0; j < 8; ++j)
        b[j][s1] = *(const longx2*)(bBase + (bc0 + j * 16 + ml) * 128 + slot);
    }
    #pragma unroll
    for (int s1 = 0; s1 < 2; ++s1)
      #pragma unroll
      for (int h = 0; h < 2; ++h)
        #pragma unroll
        for (int i = 0; i < 4; ++i)
          #pragma unroll
          for (int j = 0; j < 8; ++j)
            acc[i][j] = __builtin_amdgcn_mfma_f32_16x16x32_fp8_fp8(
                a[i][s1][h], b[j][s1][h], acc[i][j], 0, 0, 0);
    __syncthreads();
  }

  // slab: lane-major bf16, 128x256 per job. entry = w*8192+(i*8+j)*256+lane*4+p
  unsigned short* slab = Gp + (size_t)job * 32768 + w * 8192;
  #pragma unroll
  for (int i = 0; i < 4; ++i)
    #pragma unroll
    for (int j = 0; j < 8; ++j) {
      ushort4 o;
      o.x = f2bf(acc[i][j][0]); o.y = f2bf(acc[i][j][1]);
      o.z = f2bf(acc[i][j][2]); o.w = f2bf(acc[i][j][3]);
      *(ushort4*)(slab + (i * 8 + j) * 256 + lane * 4) = o;
    }
}

// ---------------------------------------------------------------------------
// K4: sum KSPLIT partials (fp32), square, weight {0,1,2} by decoded (gr,gc),
// sign by block, reduce -> atomicAdd. Grid: NJOBT*16, 2048 entries/block.
// ---------------------------------------------------------------------------
__global__ __launch_bounds__(256) void square_reduce_kernel(
    const unsigned short* __restrict__ Gp, float* __restrict__ out) {
  __shared__ float wsum[4];
  const int t = blockIdx.x >> 4;
  const int seg = blockIdx.x & 15;
  int R = 0, rem = t;
  while (rem >= 8 - (R >> 1)) { rem -= 8 - (R >> 1); ++R; }
  const int C = (R >> 1) + rem;
  const bool fullAbove = (R < 2 * C);   // every entry strictly above diagonal

  const int off0 = seg * 2048 + threadIdx.x * 8;
  const unsigned short* base = Gp + (size_t)t * (KSPLIT * 32768) + off0;
  float s[8] = {0, 0, 0, 0, 0, 0, 0, 0};
  #pragma unroll
  for (int kc = 0; kc < KSPLIT; ++kc) {
    const ushort8 v = *(const ushort8*)(base + kc * 32768);
    #pragma unroll
    for (int x = 0; x < 8; ++x) s[x] += bf2f(v[x]);
  }

  float local = 0.0f;
  if (fullAbove) {
    #pragma unroll
    for (int x = 0; x < 8; ++x) local += 2.0f * s[x] * s[x];
  } else {
    #pragma unroll
    for (int x = 0; x < 8; ++x) {
      const int off = off0 + x;
      const int wv = off >> 13;
      const int rm = off & 8191;
      const int fi = rm >> 8;             // i*8 + j
      const int l4 = rm & 255;
      const int ln = l4 >> 2, p = l4 & 3;
      const int r = (wv >> 1) * 64 + (fi >> 3) * 16 + (ln >> 4) * 4 + p;
      const int c = (wv & 1) * 128 + (fi & 7) * 16 + (ln & 15);
      const int gr = R * 128 + r, gc = C * 256 + c;
      const float wgt = (gr < gc) ? 2.0f : (gr == gc ? 1.0f : 0.0f);
      local += wgt * s[x] * s[x];
    }
  }
  const float sgn = ((R < 8) == (C < 4)) ? 1.0f : -1.0f;
  local *= sgn;

  #pragma unroll
  for (int off = 32; off > 0; off >>= 1) local += __shfl_xor(local, off);
  const int w = threadIdx.x >> 6, lane = threadIdx.x & 63;
  if (lane == 0) wsum[w] = local;
  __syncthreads();
  if (threadIdx.x == 0) {
    const float ts = wsum[0] + wsum[1] + wsum[2] + wsum[3];
    atomicAdd(out, ts * (1.0f / 16773120.0f));  // / (N*(N-1))
  }
}

extern "C" void kernel_launch(void* const* d_in, const int* in_sizes, int n_in,
                              void* d_out, int out_size, void* d_ws, size_t ws_size,
                              hipStream_t stream) {
  const float* fq = (const float*)d_in[0];
  const float* fk = (const float*)d_in[1];
  float* invq = (float*)d_ws;                                    // 16 KiB
  float* invk = invq + N_ROWS;                                   // 16 KiB
  unsigned char* Mt = (unsigned char*)d_ws + 32768;              // 8 MiB fp8
  unsigned short* Gp = (unsigned short*)(Mt + (size_t)2048 * N_ROWS);  // 36 MiB
  float* out = (float*)d_out;

  rownorm_kernel<<<dim3(N_ROWS / 4, 2), 256, 0, stream>>>(fq, fk, invq, invk, out);
  transpose_scale_kernel<<<dim3(16, 32), 256, 0, stream>>>(fq, fk, invq, invk, Mt);
  gram_grouped_kernel<<<NJOBT * KSPLIT, 256, 0, stream>>>(Mt, Gp);
  square_reduce_kernel<<<NJOBT * 16, 256, 0, stream>>>(Gp, out);
}

// Round 11
// 114.743 us; speedup vs baseline: 1.1679x; 1.1679x over previous
//
#include <hip/hip_runtime.h>
#include <stdint.h>

// N=4096, D=1024 -> M = [Q|K] : 4096 x 2048, Mt = M^T (fp8 e4m3, K-permuted)
// loss = [ sum_{a,b} s_a s_b (M^T M)_ab^2 ] / (N*(N-1)), s_a=+1 (a<1024), -1 else
// R11 = R6 (best: 116.5us) with ONE change: KSPLIT 4->8. Supplies 4.25
// resident blocks/CU (was 2.1) at identical staged bytes (133 MB) and
// identical per-CU block-iteration count (17). Tests whether the fp8 gram's
// ~67% all-idle stall (R1 counters) is co-residency-limited.
#define N_ROWS 4096
#define DIMS   1024
#define BM 128
#define BK 128         // fp8 elements per LDS row = 128 bytes
#define TG 16
#define NTRI 136
#define KSPLIT 8
#define KCHUNK 512     // 4096/KSPLIT (fp8 bytes)
#define NJOBS  (NTRI * KSPLIT) // 1088

typedef __attribute__((ext_vector_type(2))) long longx2;
typedef __attribute__((ext_vector_type(4))) float f32x4;

__device__ __forceinline__ unsigned short f2bf(float f) {
  union { float f; unsigned int u; } c; c.f = f;
  unsigned int u = c.u;
  return (unsigned short)((u + 0x7fffu + ((u >> 16) & 1u)) >> 16);
}
__device__ __forceinline__ float bf2f(unsigned short v) {
  union { float f; unsigned int u; } c; c.u = ((unsigned int)v) << 16;
  return c.f;
}
// pack 4 floats -> 4 fp8 e4m3 bytes (hardware cvt, OCP on gfx950)
__device__ __forceinline__ unsigned int pk4_fp8(float a, float b, float c, float d) {
  int v = __builtin_amdgcn_cvt_pk_fp8_f32(a, b, 0, false);
  v = __builtin_amdgcn_cvt_pk_fp8_f32(c, d, v, true);
  return (unsigned int)v;
}
// async global->LDS, 16B/lane
__device__ __forceinline__ void async_cp16(const unsigned char* g, void* lds) {
  __builtin_amdgcn_global_load_lds(
      (const __attribute__((address_space(1))) void*)g,
      (__attribute__((address_space(3))) void*)lds, 16, 0, 0);
}

// ---------------------------------------------------------------------------
// K1: inverse row norms; zero d_out. (R6-verified)
// ---------------------------------------------------------------------------
__global__ __launch_bounds__(256) void rownorm_kernel(
    const float* __restrict__ fq, const float* __restrict__ fk,
    float* __restrict__ invq, float* __restrict__ invk, float* __restrict__ out) {
  if (blockIdx.x == 0 && blockIdx.y == 0 && threadIdx.x == 0) out[0] = 0.0f;
  const int w = threadIdx.x >> 6, lane = threadIdx.x & 63;
  const int row = blockIdx.x * 4 + w;
  const float* src = blockIdx.y ? fk : fq;
  float* dst = blockIdx.y ? invk : invq;
  const float4* s4 = (const float4*)(src + (size_t)row * DIMS);
  float ss = 0.0f;
  #pragma unroll
  for (int s = 0; s < 4; ++s) {
    float4 v = s4[lane + 64 * s];
    ss += v.x * v.x + v.y * v.y + v.z * v.z + v.w * v.w;
  }
  #pragma unroll
  for (int off = 32; off > 0; off >>= 1) ss += __shfl_xor(ss, off);
  if (lane == 0) dst[row] = 1.0f / sqrtf(ss);  // eps terms cancel (~3e-9 rel)
}

// ---------------------------------------------------------------------------
// K2: Mt[a][perm(i)] = fp8(normalized), transposed via LDS. (R6-verified)
// ---------------------------------------------------------------------------
__global__ __launch_bounds__(256) void transpose_scale_kernel(
    const float* __restrict__ fq, const float* __restrict__ fk,
    const float* __restrict__ invq, const float* __restrict__ invk,
    unsigned char* __restrict__ Mt) {
  __shared__ unsigned short tile[64][260];
  const int i0 = blockIdx.x * 256;
  const int a0 = blockIdx.y * 64;
  const int w = threadIdx.x >> 6, lane = threadIdx.x & 63;
  const float* src;
  const float* inv;
  int acol;
  if (a0 < DIMS) { src = fq; inv = invq; acol = a0 + lane; }
  else           { src = fk; inv = invk; acol = a0 - DIMS + lane; }

  for (int c0 = 0; c0 < 64; c0 += 4) {
    ushort4 v;
    unsigned short* vp = (unsigned short*)&v;
    #pragma unroll
    for (int c = 0; c < 4; ++c) {
      const int i = i0 + w * 64 + c0 + c;
      vp[c] = f2bf(src[(size_t)i * DIMS + acol] * inv[i]);
    }
    *(ushort4*)&tile[lane][w * 64 + c0] = v;
  }
  __syncthreads();
  // write: lane covers i = i0 + lane*4 .. +3; K-perm pos = q*32+s1*16+s0*8+j
  const int il = (lane * 4) & 127;
  const int blk = (i0 + lane * 4) >> 7;
  const int q = (il >> 3) & 3, s0b = (il >> 5) & 1, s1b = (il >> 6) & 1;
  const int pos = q * 32 + s1b * 16 + s0b * 8 + (il & 7);
  #pragma unroll
  for (int r = 0; r < 16; ++r) {
    const int al = w * 16 + r;
    ushort4 v = *(const ushort4*)&tile[al][lane * 4];
    const unsigned int p8 = pk4_fp8(bf2f(v.x), bf2f(v.y), bf2f(v.z), bf2f(v.w));
    *(unsigned int*)(Mt + (size_t)(a0 + al) * N_ROWS + blk * 128 + pos) = p8;
  }
}

// ---------------------------------------------------------------------------
// K3: partial Gram tiles, fp8 MFMA (R6 core verbatim; only kc width changed).
// Single-buffered 32 KiB LDS, natural job order, no fences.
// ---------------------------------------------------------------------------
__global__ __launch_bounds__(256, 2) void gram_partial_kernel(
    const unsigned char* __restrict__ Mt, unsigned short* __restrict__ Gp) {
  __shared__ __align__(16) char smem[2 * BM * BK];  // 32 KiB: A + B panels

  const int t = blockIdx.x >> 3;
  const int kc = blockIdx.x & 7;
  int I = 0, rem = t;
  while (rem >= (TG - I)) { rem -= (TG - I); ++I; }
  const int J = I + rem;

  const int tid = threadIdx.x, w = tid >> 6, lane = tid & 63;

  const int isB = w >> 1;
  const int rblk = isB ? J : I;
  const int rl = lane >> 3;
  const int cl = (lane & 7) ^ rl;          // chunk swizzle (verified R1..R10)
  const bool skipStage = (isB && I == J);
  const unsigned char* gsrc0 =
      Mt + (size_t)(rblk * BM + (w & 1) * 64 + rl) * N_ROWS + kc * KCHUNK + cl * 16;
  char* ldsBase = smem + isB * 16384 + (w & 1) * 8192;
  const int bOff = (I == J) ? 0 : 16384;

  const int ml = lane & 15, quad = lane >> 4;
  const int ar0 = (w >> 1) * 64, bc0 = (w & 1) * 64;

  f32x4 acc[4][4] = {};

  for (int kk = 0; kk < KCHUNK; kk += BK) {
    if (!skipStage) {
      const unsigned char* g = gsrc0 + kk;
      #pragma unroll
      for (int s = 0; s < 8; ++s)
        async_cp16(g + (size_t)s * 8 * N_ROWS, ldsBase + s * 1024);
    }
    __syncthreads();
    longx2 a[4][2], b[4][2];
    #pragma unroll
    for (int i = 0; i < 4; ++i) {
      const int ra = (ar0 + i * 16 + ml) * BK;
      const int rb = (bc0 + i * 16 + ml) * BK;
      #pragma unroll
      for (int s1 = 0; s1 < 2; ++s1) {
        const int slot = ((quad * 2 + s1) ^ (ml & 7)) * 16;
        a[i][s1] = *(const longx2*)(smem + ra + slot);
        b[i][s1] = *(const longx2*)(smem + bOff + rb + slot);
      }
    }
    #pragma unroll
    for (int s1 = 0; s1 < 2; ++s1)
      #pragma unroll
      for (int h = 0; h < 2; ++h)
        #pragma unroll
        for (int i = 0; i < 4; ++i)
          #pragma unroll
          for (int j = 0; j < 4; ++j)
            acc[i][j] = __builtin_amdgcn_mfma_f32_16x16x32_fp8_fp8(
                a[i][s1][h], b[j][s1][h], acc[i][j], 0, 0, 0);
    __syncthreads();
  }

  // epilogue: lane-major coalesced bf16 slab (layout consistent across kc)
  unsigned short* slab = Gp + (size_t)blockIdx.x * (BM * BM) + w * 4096;
  #pragma unroll
  for (int i = 0; i < 4; ++i)
    #pragma unroll
    for (int j = 0; j < 4; ++j) {
      ushort4 o;
      o.x = f2bf(acc[i][j][0]); o.y = f2bf(acc[i][j][1]);
      o.z = f2bf(acc[i][j][2]); o.w = f2bf(acc[i][j][3]);
      *(ushort4*)(slab + (i * 4 + j) * 256 + lane * 4) = o;
    }
}

// ---------------------------------------------------------------------------
// K4: sum KSPLIT partials (fp32), square, sign/weight, reduce -> atomicAdd.
// ---------------------------------------------------------------------------
__global__ __launch_bounds__(256) void square_reduce_kernel(
    const unsigned short* __restrict__ Gp, float* __restrict__ out) {
  __shared__ float wsum[4];
  const int t = blockIdx.x >> 3;
  const int seg = blockIdx.x & 7;
  int I = 0, rem = t;
  while (rem >= (TG - I)) { rem -= (TG - I); ++I; }
  const int J = I + rem;

  const unsigned short* base =
      Gp + (size_t)t * (KSPLIT * BM * BM) + seg * 2048 + threadIdx.x * 8;
  float s[8] = {0, 0, 0, 0, 0, 0, 0, 0};
  #pragma unroll
  for (int kc = 0; kc < KSPLIT; ++kc) {
    const ushort4 v0 = *(const ushort4*)(base + kc * (BM * BM));
    const ushort4 v1 = *(const ushort4*)(base + kc * (BM * BM) + 4);
    s[0] += bf2f(v0.x); s[1] += bf2f(v0.y); s[2] += bf2f(v0.z); s[3] += bf2f(v0.w);
    s[4] += bf2f(v1.x); s[5] += bf2f(v1.y); s[6] += bf2f(v1.z); s[7] += bf2f(v1.w);
  }
  float local = 0.0f;
  #pragma unroll
  for (int x = 0; x < 8; ++x) local += s[x] * s[x];

  const float sgn = ((I < 8) == (J < 8)) ? 1.0f : -1.0f;
  local *= (I == J ? 1.0f : 2.0f) * sgn;

  #pragma unroll
  for (int off = 32; off > 0; off >>= 1) local += __shfl_xor(local, off);
  const int w = threadIdx.x >> 6, lane = threadIdx.x & 63;
  if (lane == 0) wsum[w] = local;
  __syncthreads();
  if (threadIdx.x == 0) {
    const float ts = wsum[0] + wsum[1] + wsum[2] + wsum[3];
    atomicAdd(out, ts * (1.0f / 16773120.0f));  // / (N*(N-1))
  }
}

extern "C" void kernel_launch(void* const* d_in, const int* in_sizes, int n_in,
                              void* d_out, int out_size, void* d_ws, size_t ws_size,
                              hipStream_t stream) {
  const float* fq = (const float*)d_in[0];
  const float* fk = (const float*)d_in[1];
  float* invq = (float*)d_ws;                                    // 16 KiB
  float* invk = invq + N_ROWS;                                   // 16 KiB
  unsigned char* Mt = (unsigned char*)d_ws + 32768;              // 8 MiB fp8
  unsigned short* Gp = (unsigned short*)(Mt + (size_t)2048 * N_ROWS);  // 35.7 MiB
  float* out = (float*)d_out;

  rownorm_kernel<<<dim3(N_ROWS / 4, 2), 256, 0, stream>>>(fq, fk, invq, invk, out);
  transpose_scale_kernel<<<dim3(16, 32), 256, 0, stream>>>(fq, fk, invq, invk, Mt);
  gram_partial_kernel<<<NJOBS, 256, 0, stream>>>(Mt, Gp);
  square_reduce_kernel<<<NTRI * 8, 256, 0, stream>>>(Gp, out);
}